// Round 1
// baseline (2097.526 us; speedup 1.0000x reference)
//
#include <hip/hip_runtime.h>
#include <hip/hip_bf16.h>
#include <math.h>

#define Bb 64
#define Ss 30
#define Cc 62
#define Ll 169
#define CL (Cc*Ll)          // 10478
#define GRU 64

// ---------------- K1: sq[b,s] = mean over (c,L) ----------------
__global__ __launch_bounds__(256) void k_sq(const float* __restrict__ x, float* __restrict__ sq)
{
    __shared__ float red[4];
    int bs = blockIdx.x;
    const float* p = x + (size_t)bs * CL;
    float acc = 0.f;
    for (int i = threadIdx.x; i < CL; i += 256) acc += p[i];
    for (int off = 32; off; off >>= 1) acc += __shfl_down(acc, off);
    if ((threadIdx.x & 63) == 0) red[threadIdx.x >> 6] = acc;
    __syncthreads();
    if (threadIdx.x == 0) sq[bs] = (red[0] + red[1] + red[2] + red[3]) / (float)CL;
}

// ---------------- K2: SE MLP -> a[b,s] ----------------
__global__ __launch_bounds__(64) void k_se(const float* __restrict__ sq, const float* __restrict__ w1,
                                           const float* __restrict__ w2, float* __restrict__ aout)
{
    int b = threadIdx.x;
    float sv[Ss];
    for (int s = 0; s < Ss; ++s) sv[s] = sq[b*Ss + s];
    float hid[15];
    for (int j = 0; j < 15; ++j) {
        float h = 0.f;
        for (int s = 0; s < Ss; ++s) h += sv[s] * w1[s*15 + j];
        hid[j] = fmaxf(h, 0.f);
    }
    for (int s = 0; s < Ss; ++s) {
        float o = 0.f;
        for (int j = 0; j < 15; ++j) o += hid[j] * w2[j*Ss + s];
        aout[b*Ss + s] = 1.f / (1.f + expf(-o));
    }
}

// ---------------- K3: max_seg[b,c,l] = max_s a[b,s]*x[b,s,c,l] ----------------
__global__ __launch_bounds__(256) void k_maxseg(const float* __restrict__ x, const float* __restrict__ a,
                                                float* __restrict__ ms)
{
    int idx = blockIdx.x * 256 + threadIdx.x;
    if (idx >= Bb*CL) return;
    int b = idx / CL;
    int rem = idx - b*CL;
    float m = -INFINITY;
    for (int s = 0; s < Ss; ++s) {
        float v = x[(size_t)(b*Ss + s)*CL + rem] * a[b*Ss + s];
        m = fmaxf(m, v);
    }
    ms[idx] = m;
}

// ---------------- K4: direct DFT per (b,c) row ----------------
__global__ __launch_bounds__(256) void k_dft(const float* __restrict__ ms, float* __restrict__ fre,
                                             float* __restrict__ fim)
{
    __shared__ float xr[Ll], ct[Ll], st[Ll];
    int row = blockIdx.x;
    int tid = threadIdx.x;
    if (tid < Ll) {
        xr[tid] = ms[(size_t)row*Ll + tid];
        float ang = (float)tid * (6.28318530717958647692f / (float)Ll);
        ct[tid] = cosf(ang);
        st[tid] = sinf(ang);
    }
    __syncthreads();
    if (tid < Ll) {
        int k = tid;
        float re = 0.f, im = 0.f;
        int idx = 0;
        for (int n = 0; n < Ll; ++n) {
            float v = xr[n];
            re += v * ct[idx];
            im -= v * st[idx];
            idx += k; if (idx >= Ll) idx -= Ll;
        }
        fre[(size_t)row*Ll + k] = re;
        fim[(size_t)row*Ll + k] = im;
    }
}

// ---------------- K5: adj row 61 ----------------
__global__ __launch_bounds__(64) void k_adjrow(const float* __restrict__ fre, const float* __restrict__ fim,
                                               float* __restrict__ adjr)
{
    int b = blockIdx.x / Cc;
    int j = blockIdx.x % Cc;
    int lane = threadIdx.x;
    const float* re61 = fre + (size_t)(b*Cc + 61)*Ll;
    const float* im61 = fim + (size_t)(b*Cc + 61)*Ll;
    const float* rej  = fre + (size_t)(b*Cc + j)*Ll;
    const float* imj  = fim + (size_t)(b*Cc + j)*Ll;
    float num = 0.f, den = 0.f;
    for (int l = lane; l < Ll; l += 64) {
        float ar = re61[l], ai = im61[l];
        float br = rej[l],  bi = imj[l];
        num += ai*br - ar*bi;
        den += sqrtf(ar*ar + ai*ai) * sqrtf(br*br + bi*bi);
    }
    for (int off = 32; off; off >>= 1) { num += __shfl_down(num, off); den += __shfl_down(den, off); }
    if (lane == 0) adjr[b*Cc + j] = (j == 61) ? 0.f : num / den;
}

// ---------------- K6 helpers ----------------
template<int K, int SIN, int LOUT, int SOUT, int WS>
__device__ __forceinline__ void dw_stage(const float* __restrict__ Xb, const float* __restrict__ Wl,
                                         const float* __restrict__ bias, float* __restrict__ Ab, int tid)
{
    constexpr int CH = (LOUT + 7) / 8;
    for (int u = tid; u < Cc*CH; u += 512) {
        int m = u % Cc, p0 = (u / Cc) * 8;
        const float* xr = Xb + m*SIN + p0;
        float win[8], acc[8];
#pragma unroll
        for (int r = 0; r < 8; ++r) { win[r] = xr[r]; acc[r] = 0.f; }
#pragma unroll
        for (int k = 0; k < K; ++k) {
            float wk = Wl[m*WS + k];
#pragma unroll
            for (int r = 0; r < 8; ++r) acc[r] += wk * win[(r + k) & 7];
            win[k & 7] = xr[k + 8];
        }
        float bm = bias[m];
#pragma unroll
        for (int r = 0; r < 8; ++r) if (p0 + r < LOUT) Ab[m*SOUT + p0 + r] = acc[r] + bm;
    }
}

template<int LOUT, int SIN, int SOUT>
__device__ __forceinline__ void pw_stage(const float* __restrict__ Yb, const float* __restrict__ Wl,
                                         const float* __restrict__ bias, float* __restrict__ Zb, int tid)
{
    constexpr int CH = (LOUT + 7) / 8;
    for (int u = tid; u < Cc*CH; u += 512) {
        int o = u % Cc, p0 = (u / Cc) * 8;
        float acc[8];
#pragma unroll
        for (int r = 0; r < 8; ++r) acc[r] = 0.f;
        for (int i = 0; i < Cc; ++i) {
            float w = Wl[o*63 + i];
            const float2* yp = reinterpret_cast<const float2*>(Yb + i*SIN + p0);
#pragma unroll
            for (int q = 0; q < 4; ++q) {
                float2 y = yp[q];
                acc[2*q]   += w * y.x;
                acc[2*q+1] += w * y.y;
            }
        }
        float bo = bias[o];
#pragma unroll
        for (int r = 0; r < 8; ++r) if (p0 + r < LOUT) Zb[o*SOUT + p0 + r] = acc[r] + bo;
    }
}

// ---------------- K6: fused dsc chain per (b,t), outputs d61[(t*64+b)*62 + j] ----------------
__global__ __launch_bounds__(512) void k_dsc(const float* __restrict__ x,
    const float* __restrict__ dwk1, const float* __restrict__ dwb1,
    const float* __restrict__ pwk1, const float* __restrict__ pwb1,
    const float* __restrict__ dwk2, const float* __restrict__ dwb2,
    const float* __restrict__ pwk2, const float* __restrict__ pwb2,
    const float* __restrict__ dwk3, const float* __restrict__ dwb3,
    const float* __restrict__ pwk3, const float* __restrict__ pwb3,
    float* __restrict__ d61)
{
    __shared__ float X[10486];     // xt, then z1 (stride 106), then z2 (stride 76); +8 pad
    __shared__ float A[6580];      // y1 (106), y2 (76), y3 (62); +8 pad
    __shared__ float W[62*65];     // stage weights, padded strides
    const int tid = threadIdx.x;
    const int bt = blockIdx.x, t = bt >> 6, b = bt & 63;
    const float* xrow = x + (size_t)(b*Ss + t) * CL;

    for (int i = tid; i < CL; i += 512) X[i] = xrow[i];
    for (int i = tid; i < Cc*64; i += 512) W[(i >> 6)*65 + (i & 63)] = dwk1[i];
    __syncthreads();
    dw_stage<64,169,106,106,65>(X, W, dwb1, A, tid);
    __syncthreads();
    for (int i = tid; i < Cc*Cc; i += 512) W[(i/Cc)*63 + (i%Cc)] = pwk1[i];
    __syncthreads();
    pw_stage<106,106,106>(A, W, pwb1, X, tid);
    __syncthreads();
    for (int i = tid; i < Cc*32; i += 512) W[(i >> 5)*33 + (i & 31)] = dwk2[i];
    __syncthreads();
    dw_stage<32,106,75,76,33>(X, W, dwb2, A, tid);
    __syncthreads();
    for (int i = tid; i < Cc*Cc; i += 512) W[(i/Cc)*63 + (i%Cc)] = pwk2[i];
    __syncthreads();
    pw_stage<75,76,76>(A, W, pwb2, X, tid);
    __syncthreads();
    for (int i = tid; i < Cc*14; i += 512) W[(i/14)*15 + (i%14)] = dwk3[i];
    __syncthreads();
    dw_stage<14,76,62,62,15>(X, W, dwb3, A, tid);
    __syncthreads();
    if (tid < Cc) {
        float accv = pwb3[61];
        for (int i = 0; i < Cc; ++i) accv += pwk3[61*Cc + i] * A[i*Cc + tid];
        d61[(size_t)bt*Cc + tid] = accv;
    }
}

// ---------------- K7: adj_t row, v, g, pre-gates per (b,t) ----------------
__global__ __launch_bounds__(256) void k_g(const float* __restrict__ x, const float* __restrict__ d61,
    const float* __restrict__ adjr, const float* __restrict__ gcn_w, const float* __restrict__ gcn_b,
    const float* __restrict__ w_r, const float* __restrict__ w_u, const float* __restrict__ w_c,
    float* __restrict__ preR, float* __restrict__ preU, float* __restrict__ preC)
{
    __shared__ float adjt[Cc];
    __shared__ float v[Ll];
    __shared__ float g[GRU];
    int bt = blockIdx.x, t = bt >> 6, b = bt & 63;
    int tid = threadIdx.x;
    if (tid < Cc) {
        float sv = d61[(size_t)bt*Cc + tid] + adjr[b*Cc + tid];
        adjt[tid] = 1.f / (1.f + expf(-sv));
    }
    __syncthreads();
    if (tid < Ll) {
        const float* xp = x + (size_t)(b*Ss + t)*CL + tid;
        float acc = 0.f;
        for (int j = 0; j < Cc; ++j) acc += adjt[j] * xp[j*Ll];
        v[tid] = acc;
    }
    __syncthreads();
    if (tid < GRU) {
        float acc = gcn_b[tid];
        for (int l = 0; l < Ll; ++l) acc += v[l] * gcn_w[l*GRU + tid];
        g[tid] = acc;
    }
    __syncthreads();
    if (tid < GRU) {
        float ar = 0.f, au = 0.f, ac = 0.f;
        for (int i = 0; i < GRU; ++i) {
            float gi = g[i];
            ar += gi * w_r[i*GRU + tid];
            au += gi * w_u[i*GRU + tid];
            ac += gi * w_c[i*GRU + tid];
        }
        preR[(size_t)bt*GRU + tid] = ar;
        preU[(size_t)bt*GRU + tid] = au;
        preC[(size_t)bt*GRU + tid] = ac;
    }
}

// ---------------- K8: GRU scan over t for rows (b, c=61) ----------------
__global__ __launch_bounds__(64) void k_gru(const float* __restrict__ preR, const float* __restrict__ preU,
    const float* __restrict__ preC,
    const float* __restrict__ w_r, const float* __restrict__ wb_r,
    const float* __restrict__ w_u, const float* __restrict__ wb_u,
    const float* __restrict__ w_c, const float* __restrict__ wb_c,
    const float* __restrict__ b_r, const float* __restrict__ b_u, const float* __restrict__ b_c,
    float* __restrict__ out)
{
    __shared__ float W2r[GRU*GRU], W2u[GRU*GRU], W2c[GRU*GRU];
    __shared__ float h[GRU], rh[GRU];
    int b = blockIdx.x, o = threadIdx.x;
    for (int i = 0; i < GRU; ++i) {
        W2r[i*GRU + o] = w_r[(GRU + i)*GRU + o];
        W2u[i*GRU + o] = w_u[(GRU + i)*GRU + o];
        W2c[i*GRU + o] = w_c[(GRU + i)*GRU + o];
    }
    float cr = wb_r[o] + b_r[o];
    float cu = wb_u[o] + b_u[o];
    float cc = wb_c[o] + b_c[o];
    float hreg = 0.f;
    h[o] = 0.f;
    __syncthreads();
    for (int t = 0; t < Ss; ++t) {
        size_t base = (size_t)(t*Bb + b)*GRU + o;
        float ar = preR[base] + cr;
        float au = preU[base] + cu;
        for (int i = 0; i < GRU; ++i) {
            float hi = h[i];
            ar += hi * W2r[i*GRU + o];
            au += hi * W2u[i*GRU + o];
        }
        float r = 1.f / (1.f + expf(-ar));
        float u = 1.f / (1.f + expf(-au));
        rh[o] = r * hreg;
        __syncthreads();
        float ac = preC[base] + cc;
        for (int i = 0; i < GRU; ++i) ac += rh[i] * W2c[i*GRU + o];
        float ct = tanhf(ac);
        hreg = u * hreg + (1.f - u) * ct;
        __syncthreads();
        h[o] = hreg;
        __syncthreads();
    }
    out[b*GRU + o] = hreg;
}

// ---------------- launcher ----------------
extern "C" void kernel_launch(void* const* d_in, const int* in_sizes, int n_in,
                              void* d_out, int out_size, void* d_ws, size_t ws_size,
                              hipStream_t stream)
{
    const float* x     = (const float*)d_in[0];
    const float* se_w1 = (const float*)d_in[1];
    const float* se_w2 = (const float*)d_in[2];
    const float* dwk1  = (const float*)d_in[3];
    const float* dwb1  = (const float*)d_in[4];
    const float* pwk1  = (const float*)d_in[5];
    const float* pwb1  = (const float*)d_in[6];
    const float* dwk2  = (const float*)d_in[7];
    const float* dwb2  = (const float*)d_in[8];
    const float* pwk2  = (const float*)d_in[9];
    const float* pwb2  = (const float*)d_in[10];
    const float* dwk3  = (const float*)d_in[11];
    const float* dwb3  = (const float*)d_in[12];
    const float* pwk3  = (const float*)d_in[13];
    const float* pwb3  = (const float*)d_in[14];
    const float* gcn_w = (const float*)d_in[15];
    const float* gcn_b = (const float*)d_in[16];
    const float* w_r   = (const float*)d_in[17];
    const float* wb_r  = (const float*)d_in[18];
    const float* w_u   = (const float*)d_in[19];
    const float* wb_u  = (const float*)d_in[20];
    const float* w_c   = (const float*)d_in[21];
    const float* wb_c  = (const float*)d_in[22];
    const float* b_r   = (const float*)d_in[23];
    const float* b_u   = (const float*)d_in[24];
    const float* b_c   = (const float*)d_in[25];
    float* out = (float*)d_out;

    float* ws = (float*)d_ws;
    float* sq   = ws;                    // 1920
    float* aw   = sq   + 1920;           // 1920
    float* msb  = aw   + 1920;           // 670592
    float* fre  = msb  + 670592;         // 670592
    float* fim  = fre  + 670592;         // 670592
    float* adjr = fim  + 670592;         // 3968
    float* d61  = adjr + 3968;           // 119040
    float* preR = d61  + 119040;         // 122880
    float* preU = preR + 122880;         // 122880
    float* preC = preU + 122880;         // 122880

    k_sq<<<Bb*Ss, 256, 0, stream>>>(x, sq);
    k_se<<<1, 64, 0, stream>>>(sq, se_w1, se_w2, aw);
    k_maxseg<<<(Bb*CL + 255)/256, 256, 0, stream>>>(x, aw, msb);
    k_dft<<<Bb*Cc, 256, 0, stream>>>(msb, fre, fim);
    k_adjrow<<<Bb*Cc, 64, 0, stream>>>(fre, fim, adjr);
    k_dsc<<<Ss*Bb, 512, 0, stream>>>(x, dwk1, dwb1, pwk1, pwb1, dwk2, dwb2, pwk2, pwb2,
                                     dwk3, dwb3, pwk3, pwb3, d61);
    k_g<<<Ss*Bb, 256, 0, stream>>>(x, d61, adjr, gcn_w, gcn_b, w_r, w_u, w_c, preR, preU, preC);
    k_gru<<<Bb, 64, 0, stream>>>(preR, preU, preC, w_r, wb_r, w_u, wb_u, w_c, wb_c,
                                 b_r, b_u, b_c, out);
}